// Round 1
// 576.707 us; speedup vs baseline: 1.2193x; 1.2193x over previous
//
#include <hip/hip_runtime.h>
#include <hip/hip_bf16.h>

#define B_N 4096
#define L_N 50
#define D_N 64

// d_ws word layout (4-byte word offsets; packed-f16-pair sections are u32, rest f32)
#define W1P  0       // [64][64] u32: pair i of k, out e -> {w1[e][2i], w1[e][2i+1]} as f16x2
#define W2P  4096    // [32][64] u32
#define A1P  6144    // [32][64] u32 (o-part of att1_w: cols 0..63)
#define A2P  8192    // [32][64] u32
#define A1TU 10240   // [64][64] f32: att1_w[e][64+i] transposed -> [i][e] (ur-part, for c1)
#define W3   14336   // [64] f32
#define B1   14400   // [64] f32
#define B2   14464   // [64] f32
#define AB1  14528   // [64] f32
#define AB2  14592   // [64] f32
#define FLAG 14656   // 1.0f if inputs fp32, 0.0f if bf16
#define WS_WORDS 14657   // 58,628 bytes needed in d_ws

typedef _Float16 f16x2 __attribute__((ext_vector_type(2)));

__device__ __forceinline__ float bflo(unsigned p) { return __uint_as_float(p << 16); }
__device__ __forceinline__ float bfhi(unsigned p) { return __uint_as_float(p & 0xffff0000u); }
__device__ __forceinline__ float bf1(unsigned short u) { return __uint_as_float(((unsigned)u) << 16); }
__device__ __forceinline__ unsigned short f2bf(float f) {
    unsigned u = __float_as_uint(f);
    u += 0x7fffu + ((u >> 16) & 1u);   // RNE (finite values only)
    return (unsigned short)(u >> 16);
}
__device__ __forceinline__ f16x2 bch(unsigned u) { return __builtin_bit_cast(f16x2, u); }

// fast f32x2 -> packed f16x2 (RTZ) for activations
#if __has_builtin(__builtin_amdgcn_cvt_pkrtz)
__device__ __forceinline__ unsigned pkr(float a, float b) {
    return __builtin_bit_cast(unsigned, __builtin_amdgcn_cvt_pkrtz(a, b));
}
#else
__device__ __forceinline__ unsigned pkr(float a, float b) {
    f16x2 h; h.x = (_Float16)a; h.y = (_Float16)b;
    return __builtin_bit_cast(unsigned, h);
}
#endif
// RNE pack for weights (prep only, cost-free)
__device__ __forceinline__ unsigned pkrne(float a, float b) {
    f16x2 h; h.x = (_Float16)a; h.y = (_Float16)b;
    return __builtin_bit_cast(unsigned, h);
}

// 2-way f16 dot with f32 accumulate: v_dot2_f32_f16 (2 MACs / VALU instr)
#if __has_builtin(__builtin_amdgcn_fdot2)
#define DOT2(a, b, c) __builtin_amdgcn_fdot2((a), (b), (c), false)
#else
__device__ __forceinline__ float DOT2(f16x2 a, f16x2 b, float c) {
    return c + (float)a.x * (float)b.x + (float)a.y * (float)b.y;
}
#endif

// read element i of a tensor whose on-device dtype is fp32 (isf=1) or bf16 (isf=0)
__device__ __forceinline__ float rdv(const void* p, long i, int isf) {
    return isf ? ((const float*)p)[i] : bf1(((const unsigned short*)p)[i]);
}

// Detect dtype via wave ballot, convert weights into packed-f16-pair (and c1 fp32) layout.
__global__ void prep_kernel(const void* __restrict__ w1, const void* __restrict__ b1,
                            const void* __restrict__ w2, const void* __restrict__ b2,
                            const void* __restrict__ a1, const void* __restrict__ ab1,
                            const void* __restrict__ a2, const void* __restrict__ ab2,
                            const void* __restrict__ w3, unsigned* __restrict__ Wu) {
    float* Wf = (float*)Wu;
    __shared__ int sfl;
    if (threadIdx.x < 64) {
        // Even-index shorts: if data is bf16 these ARE w_r1 values (|v|<=0.089);
        // if fp32 they are low mantissa bits -> ~49% land in range. Ballot instead
        // of the old serial 128-iter loop (that loop ran in EVERY block).
        const unsigned short* s = (const unsigned short*)w1;
        float v = bf1(s[2 * threadIdx.x]);
        int ok = (v == v) && (fabsf(v) <= 0.25f);
        unsigned long long m = __ballot(ok);
        if (threadIdx.x == 0) sfl = (__popcll(m) >= 56) ? 0 : 1;   // 0 = bf16, 1 = fp32
    }
    __syncthreads();
    const int isf = sfl;
    const int t = blockIdx.x * 256 + threadIdx.x;
    if (t >= WS_WORDS) return;
    if (t == FLAG) { Wf[FLAG] = (float)isf; return; }
    if (t < 4096) {                 // W1P
        int i = t >> 6, e = t & 63;
        Wu[W1P + t] = pkrne(rdv(w1, e * 128 + 2 * i, isf), rdv(w1, e * 128 + 2 * i + 1, isf));
    } else if (t < 6144) {          // W2P
        int q = t - 4096, i = q >> 6, e = q & 63;
        Wu[W2P + q] = pkrne(rdv(w2, e * 64 + 2 * i, isf), rdv(w2, e * 64 + 2 * i + 1, isf));
    } else if (t < 8192) {          // A1P (o-part)
        int q = t - 6144, i = q >> 6, e = q & 63;
        Wu[A1P + q] = pkrne(rdv(a1, e * 128 + 2 * i, isf), rdv(a1, e * 128 + 2 * i + 1, isf));
    } else if (t < 10240) {         // A2P
        int q = t - 8192, i = q >> 6, e = q & 63;
        Wu[A2P + q] = pkrne(rdv(a2, e * 64 + 2 * i, isf), rdv(a2, e * 64 + 2 * i + 1, isf));
    } else if (t < 14336) {         // A1TU (ur-part, fp32)
        int q = t - 10240, i = q >> 6, e = q & 63;
        Wf[A1TU + q] = rdv(a1, e * 128 + 64 + i, isf);
    } else if (t < 14400) Wf[t] = rdv(w3, t - 14336, isf);
    else if (t < 14464) Wf[t] = rdv(b1, t - 14400, isf);
    else if (t < 14528) Wf[t] = rdv(b2, t - 14464, isf);
    else if (t < 14592) Wf[t] = rdv(ab1, t - 14528, isf);
    else if (t < FLAG)  Wf[t] = rdv(ab2, t - 14592, isf);
}

// One wave per batch row b; lane = history position l.
// x / y / a1 activations live in registers as packed f16 pairs (v_dot2_f32_f16 inner
// loops). Only genuinely cross-lane data stays in LDS: fp32 o (final transpose read),
// ur, c1, attw. LDS/block ~17.7 KB -> 9 waves/CU (was 26.6 KB -> 6).
__launch_bounds__(64, 3)   // cap VGPR <= 170 so LDS (9 blocks/CU) stays the binding limit
__global__ void agg_kernel(const int* __restrict__ nodes, const int* __restrict__ history,
                           const int* __restrict__ ratings, const int* __restrict__ lengths,
                           const void* __restrict__ u2e,
                           const void* __restrict__ r2e,
                           const void* __restrict__ rating2e,
                           const unsigned* __restrict__ Wu,
                           void* __restrict__ out) {
    __shared__ float obuf[64 * 66];   // fp32 o rows, stride 66 (bank-conflict-free transpose read)
    __shared__ float ur_s[64];
    __shared__ float c1_s[64];
    __shared__ float attw_s[64];
    const float* Wf = (const float*)Wu;

    const int b = blockIdx.x;
    const int l = threadIdx.x;
    const int lc = min(l, L_N - 1);
    const int node = nodes[b];
    const int lenb = lengths[b];
    const int isf = (Wf[FLAG] != 0.0f) ? 1 : 0;   // wave-uniform

    // user embedding row (uniform row, lane d=l loads one element)
    ur_s[l] = rdv(u2e, ((long)node << 6) + l, isf);

    // gather x = [r2e[hist], rating2e[rat]] into registers as packed f16 pairs
    unsigned xp[64];
    {
        const int h = history[b * L_N + lc];
        const int r = ratings[b * L_N + lc];
        if (!isf) {
            const uint4* pu = (const uint4*)((const unsigned short*)r2e + ((long)h << 6));
            const uint4* pv = (const uint4*)((const unsigned short*)rating2e + ((long)r << 6));
#pragma unroll
            for (int k = 0; k < 8; ++k) {
                uint4 t = pu[k];
                xp[4 * k]     = pkr(bflo(t.x), bfhi(t.x));
                xp[4 * k + 1] = pkr(bflo(t.y), bfhi(t.y));
                xp[4 * k + 2] = pkr(bflo(t.z), bfhi(t.z));
                xp[4 * k + 3] = pkr(bflo(t.w), bfhi(t.w));
            }
#pragma unroll
            for (int k = 0; k < 8; ++k) {
                uint4 t = pv[k];
                xp[32 + 4 * k]     = pkr(bflo(t.x), bfhi(t.x));
                xp[32 + 4 * k + 1] = pkr(bflo(t.y), bfhi(t.y));
                xp[32 + 4 * k + 2] = pkr(bflo(t.z), bfhi(t.z));
                xp[32 + 4 * k + 3] = pkr(bflo(t.w), bfhi(t.w));
            }
        } else {
            const float4* pu = (const float4*)((const float*)r2e + ((long)h << 6));
            const float4* pv = (const float4*)((const float*)rating2e + ((long)r << 6));
#pragma unroll
            for (int k = 0; k < 16; ++k) {
                float4 t = pu[k];
                xp[2 * k] = pkr(t.x, t.y);
                xp[2 * k + 1] = pkr(t.z, t.w);
            }
#pragma unroll
            for (int k = 0; k < 16; ++k) {
                float4 t = pv[k];
                xp[32 + 2 * k] = pkr(t.x, t.y);
                xp[32 + 2 * k + 1] = pkr(t.z, t.w);
            }
        }
    }
    __syncthreads();   // ur_s ready

    // c1[e] = att1_b[e] + sum_i att1_w[e, 64+i] * ur[i]   (lane = e, once per block)
    {
        float c = Wf[AB1 + l];
#pragma unroll 8
        for (int i = 0; i < 64; ++i) c += Wf[A1TU + i * 64 + l] * ur_s[i];
        c1_s[l] = c;
    }
    __syncthreads();   // c1_s ready (read cross-lane in att1)

    float acc[64];

    // ---- layer 1: x(128) -> y(64), f16 dot2 ----
#pragma unroll
    for (int e = 0; e < 64; ++e) acc[e] = Wf[B1 + e];
#pragma unroll 2
    for (int i = 0; i < 64; ++i) {
        const f16x2 x = bch(xp[i]);
        const unsigned* wr = &Wu[W1P + i * 64];
#pragma unroll
        for (int e = 0; e < 64; ++e) acc[e] = DOT2(x, bch(wr[e]), acc[e]);
    }
    unsigned yp[32];
#pragma unroll
    for (int e2 = 0; e2 < 32; ++e2)
        yp[e2] = pkr(fmaxf(acc[2 * e2], 0.f), fmaxf(acc[2 * e2 + 1], 0.f));

    // ---- layer 2: y(64) -> o(64) ----
#pragma unroll
    for (int e = 0; e < 64; ++e) acc[e] = Wf[B2 + e];
#pragma unroll 2
    for (int i = 0; i < 32; ++i) {
        const f16x2 x = bch(yp[i]);
        const unsigned* wr = &Wu[W2P + i * 64];
#pragma unroll
        for (int e = 0; e < 64; ++e) acc[e] = DOT2(x, bch(wr[e]), acc[e]);
    }
    unsigned op[32];
#pragma unroll
    for (int e2 = 0; e2 < 32; ++e2) {
        float a = fmaxf(acc[2 * e2], 0.f), c2 = fmaxf(acc[2 * e2 + 1], 0.f);
        obuf[l * 66 + 2 * e2] = a;          // fp32 for the final weighted sum
        obuf[l * 66 + 2 * e2 + 1] = c2;
        op[e2] = pkr(a, c2);                // f16 pairs for the att path
    }

    // ---- att1: a1 = relu(att1_w[:, :64] @ o + c1) ----
#pragma unroll
    for (int e = 0; e < 64; ++e) acc[e] = c1_s[e];
#pragma unroll 2
    for (int i = 0; i < 32; ++i) {
        const f16x2 x = bch(op[i]);
        const unsigned* wr = &Wu[A1P + i * 64];
#pragma unroll
        for (int e = 0; e < 64; ++e) acc[e] = DOT2(x, bch(wr[e]), acc[e]);
    }
#pragma unroll
    for (int e2 = 0; e2 < 32; ++e2)
        yp[e2] = pkr(fmaxf(acc[2 * e2], 0.f), fmaxf(acc[2 * e2 + 1], 0.f));

    // ---- att2 ----
#pragma unroll
    for (int e = 0; e < 64; ++e) acc[e] = Wf[AB2 + e];
#pragma unroll 2
    for (int i = 0; i < 32; ++i) {
        const f16x2 x = bch(yp[i]);
        const unsigned* wr = &Wu[A2P + i * 64];
#pragma unroll
        for (int e = 0; e < 64; ++e) acc[e] = DOT2(x, bch(wr[e]), acc[e]);
    }

    // ---- att3: score (att3_b cancels in softmax) ----
    float s0 = 0.f, s1 = 0.f, s2 = 0.f, s3 = 0.f;
#pragma unroll
    for (int e = 0; e < 64; e += 4) {
        s0 += fmaxf(acc[e], 0.f) * Wf[W3 + e];
        s1 += fmaxf(acc[e + 1], 0.f) * Wf[W3 + e + 1];
        s2 += fmaxf(acc[e + 2], 0.f) * Wf[W3 + e + 2];
        s3 += fmaxf(acc[e + 3], 0.f) * Wf[W3 + e + 3];
    }
    const float score = (s0 + s1) + (s2 + s3);

    // ---- masked softmax over lanes ----
    const bool valid = (l < lenb);   // lenb <= 50, also masks l in [50,64)
    float mx = valid ? score : -1e30f;
#pragma unroll
    for (int m = 32; m > 0; m >>= 1) mx = fmaxf(mx, __shfl_xor(mx, m, 64));
    const float pw = valid ? __expf(score - mx) : 0.f;
    float sum = pw;
#pragma unroll
    for (int m = 32; m > 0; m >>= 1) sum += __shfl_xor(sum, m, 64);
    attw_s[l] = pw / sum;
    __syncthreads();   // attw + obuf visible

    // ---- out[b][d] = sum_l attw[l] * o[l][d]  (lane = d, transpose read) ----
    float od = 0.f;
#pragma unroll 2
    for (int j = 0; j < L_N; ++j) od += attw_s[j] * obuf[j * 66 + l];
    if (isf) ((float*)out)[((long)b << 6) + l] = od;
    else     ((unsigned short*)out)[((long)b << 6) + l] = f2bf(od);
}

extern "C" void kernel_launch(void* const* d_in, const int* in_sizes, int n_in,
                              void* d_out, int out_size, void* d_ws, size_t ws_size,
                              hipStream_t stream) {
    const int* nodes = (const int*)d_in[0];
    const int* history = (const int*)d_in[1];
    const int* ratings = (const int*)d_in[2];
    const int* lengths = (const int*)d_in[3];
    const void* u2e = d_in[4];
    const void* r2e = d_in[5];
    const void* rating2e = d_in[6];
    const void* w1 = d_in[7];
    const void* b1 = d_in[8];
    const void* w2 = d_in[9];
    const void* b2 = d_in[10];
    const void* a1 = d_in[11];
    const void* ab1 = d_in[12];
    const void* a2 = d_in[13];
    const void* ab2 = d_in[14];
    const void* w3 = d_in[15];
    // d_in[16] = att3_b: additive constant on pre-softmax scores -> cancels; unused.
    unsigned* W = (unsigned*)d_ws;   // needs 58,628 bytes

    prep_kernel<<<(WS_WORDS + 255) / 256, 256, 0, stream>>>(w1, b1, w2, b2, a1, ab1, a2, ab2, w3, W);
    agg_kernel<<<B_N, 64, 0, stream>>>(nodes, history, ratings, lengths, u2e, r2e, rating2e, W, d_out);
}